// Round 22
// baseline (161.850 us; speedup 1.0000x reference)
//
#include <hip/hip_runtime.h>
#include <hip/hip_bf16.h>
#include <math.h>

namespace {

constexpr int kB = 16, kN = 576, kC = 768, kH = 12, kP = 16;
constexpr int kM = kB * kN;          // 9216 rows

typedef __attribute__((ext_vector_type(8))) __bf16 bf16x8;
typedef __attribute__((ext_vector_type(4))) float  f32x4;
typedef __attribute__((ext_vector_type(8))) unsigned short u16x8;

__device__ inline unsigned short f2bf(float f) {
  __bf16 h = (__bf16)f;
  return __builtin_bit_cast(unsigned short, h);
}
__device__ inline float bf2f(unsigned short u) {
  unsigned int x = ((unsigned int)u) << 16;
  return __builtin_bit_cast(float, x);
}
__device__ inline unsigned int pk2bf(float lo, float hi) {
  return (unsigned int)f2bf(lo) | ((unsigned int)f2bf(hi) << 16);
}
// XCD-contiguous bijective remap (nwg % 8 == 0)
__device__ inline int xcd_swz(int hw, int nwg) {
  const int per = nwg >> 3;
  return (hw & 7) * per + (hw >> 3);
}

#define GLDS16(src, dst) __builtin_amdgcn_global_load_lds( \
    (const __attribute__((address_space(1))) unsigned int*)(src), \
    (__attribute__((address_space(3))) unsigned int*)(dst), 16, 0, 0)

// fused fp32->bf16 for x (6912 blocks), qkv_w (1728), proj_w (576)
__global__ __launch_bounds__(256)
void cvt3(const float* __restrict__ x, const float* __restrict__ wq,
          const float* __restrict__ wp, unsigned short* __restrict__ xo,
          unsigned short* __restrict__ wqo, unsigned short* __restrict__ wpo) {
  const int bid = blockIdx.x;
  const float* in; unsigned short* out; int base;
  if (bid < 6912)       { in = x;  out = xo;  base = bid; }
  else if (bid < 8640)  { in = wq; out = wqo; base = bid - 6912; }
  else                  { in = wp; out = wpo; base = bid - 8640; }
  const int i = base * 256 + threadIdx.x;
  const float4 v = ((const float4*)in)[i];
  ((ushort4*)out)[i] = make_ushort4(f2bf(v.x), f2bf(v.y), f2bf(v.z), f2bf(v.w));
}

// Y[M,Nd] = A[M,KD](bf16) @ W[Nd,KD](bf16)^T. OB=1: bf16 out; OB=0: f32 out + bias.
// 128x128 tile, BK=64 (KD/64 fully-unrolled steps). A: single 16 KB LDS buffer,
// register-staged prefetch (4 sites = FULL 128x64 tile; R21 bug was 2 sites) +
// write-side XOR swizzle (R14-verified 0-conflict). B: NO LDS -- fragments
// loaded DIRECTLY from global (W panels L2-resident), prefetched 1 step ahead.
template<int OB, int KD>
__global__ __launch_bounds__(256)
void gemm_bf16(const unsigned short* __restrict__ A, const unsigned short* __restrict__ W,
               const float* __restrict__ bias, void* __restrict__ Yv, int Nd) {
  __shared__ __align__(16) unsigned short As[8192];   // 128 rows x 64 k, swizzled
  const int tid  = threadIdx.x;
  const int wv   = tid >> 6, lane = tid & 63;
  const int gx   = Nd >> 7;
  const int lg   = xcd_swz(blockIdx.x, gridDim.x);
  const long bm  = (long)(lg / gx) * 128;
  const long bn  = (long)(lg % gx) * 128;
  const int wr   = (wv >> 1) * 64;
  const int wc   = (wv & 1) * 64;
  const int row15 = lane & 15, kg = lane >> 4;

  // A staging: 1024 16B-units per K-step; unit u = site*256+tid -> row=u>>3, slot=u&7
  u16x8 ra[4];
  auto loadA = [&](int kt) {
#pragma unroll
    for (int site = 0; site < 4; ++site) {
      const int u = site * 256 + tid;
      const int row = u >> 3, slot = u & 7;
      ra[site] = *(const u16x8*)(A + (bm + row) * (long)KD + kt + slot * 8);
    }
  };
  auto writeA = [&]() {
#pragma unroll
    for (int site = 0; site < 4; ++site) {
      const int u = site * 256 + tid;
      const int row = u >> 3, slot = u & 7;
      *(u16x8*)(As + row * 64 + ((slot ^ (row & 7)) << 3)) = ra[site];
    }
  };

  // B fragment rows (global, bf16): row = bn + wc + ni*16 + row15
  const unsigned short* wrow[4];
#pragma unroll
  for (int ni = 0; ni < 4; ++ni)
    wrow[ni] = W + (bn + wc + ni * 16 + row15) * (long)KD;

  auto loadB = [&](int kt, bf16x8 (&dst)[4][2]) {
#pragma unroll
    for (int ni = 0; ni < 4; ++ni)
#pragma unroll
      for (int ks = 0; ks < 2; ++ks)
        dst[ni][ks] = *(const bf16x8*)(wrow[ni] + kt + (ks * 4 + kg) * 8);
  };

  float bvpre[4] = {0.0f, 0.0f, 0.0f, 0.0f};
  if constexpr (!OB) {
#pragma unroll
    for (int ni = 0; ni < 4; ++ni) bvpre[ni] = bias[bn + wc + ni * 16 + row15];
  }

  f32x4 acc[4][4] = {};
  bf16x8 bcur[4][2], bnxt[4][2];
  loadA(0);
  writeA();                      // compiler inserts vmcnt waits (data dep)
  loadB(0, bcur);

  constexpr int nt = KD >> 6;    // 12 steps, fully unrolled (KD compile-time)
  const int sw8 = row15 & 7;
#pragma unroll
  for (int t = 0; t < nt; ++t) {
    __syncthreads();             // B1: A tile t writes visible to all waves
    if (t + 1 < nt) {
      loadA((t + 1) << 6);       // issue early; lands under MFMA
      loadB((t + 1) << 6, bnxt);
    }

    bf16x8 af[4][2];
#pragma unroll
    for (int mi = 0; mi < 4; ++mi)
#pragma unroll
      for (int ks = 0; ks < 2; ++ks)
        af[mi][ks] = *(const bf16x8*)(&As[(wr + mi * 16 + row15) * 64 +
                                          (((ks * 4 + kg) ^ sw8) << 3)]);
    __builtin_amdgcn_s_setprio(1);
#pragma unroll
    for (int ks = 0; ks < 2; ++ks)
#pragma unroll
      for (int mi = 0; mi < 4; ++mi)
#pragma unroll
        for (int ni = 0; ni < 4; ++ni)
          acc[mi][ni] = __builtin_amdgcn_mfma_f32_16x16x32_bf16(af[mi][ks], bcur[ni][ks],
                                                                acc[mi][ni], 0, 0, 0);
    __builtin_amdgcn_s_setprio(0);
    __syncthreads();             // B2: all reads of A tile t done
    if (t + 1 < nt) {
      writeA();                  // waits on A loads via data dep
#pragma unroll
      for (int ni = 0; ni < 4; ++ni)
#pragma unroll
        for (int ks = 0; ks < 2; ++ks)
          bcur[ni][ks] = bnxt[ni][ks];   // renamed away by full unroll
    }
  }

  const int r4 = kg * 4;
#pragma unroll
  for (int ni = 0; ni < 4; ++ni) {
    const long col = bn + wc + ni * 16 + row15;
    if constexpr (OB) {
      unsigned short* Y = (unsigned short*)Yv;
#pragma unroll
      for (int mi = 0; mi < 4; ++mi)
#pragma unroll
        for (int j = 0; j < 4; ++j)
          Y[(bm + wr + mi * 16 + r4 + j) * (long)Nd + col] = f2bf(acc[mi][ni][j]);
    } else {
      float* Y = (float*)Yv;
#pragma unroll
      for (int mi = 0; mi < 4; ++mi)
#pragma unroll
        for (int j = 0; j < 4; ++j)
          Y[(bm + wr + mi * 16 + r4 + j) * (long)Nd + col] = acc[mi][ni][j] + bvpre[ni];
    }
  }
}

// Static-shift softmax: p = exp(s - 10). No max tracking, no rescale, no cross-lane
// per chunk; per-lane partial sum only. Exact up to common scale (normalized at end).
__device__ inline void softmax_group_static(f32x4 (&c)[4], float& lsum,
                                            unsigned short* pl,
                                            const int kg, const int sw) {
  float psum = 0.0f;
#pragma unroll
  for (int kb = 0; kb < 4; ++kb) {
    const float p0 = __expf(c[kb][0] - 10.0f);
    const float p1 = __expf(c[kb][1] - 10.0f);
    const float p2 = __expf(c[kb][2] - 10.0f);
    const float p3 = __expf(c[kb][3] - 10.0f);
    psum += (p0 + p1) + (p2 + p3);
    const int off = (((kb * 2 + (kg >> 1)) ^ sw) << 3) + (kg & 1) * 4;
    *(uint2*)(pl + off) = make_uint2(pk2bf(p0, p1), pk2bf(p2, p3));
  }
  lsum += psum;
}

// MFMA flash attention with gated 16-key prefix (R18-verified, frozen).
// Block = 192 thr (3 waves); each wave owns THREE 16-query groups (48 q/wave,
// 144 q/block). KV chunk = 64 keys; ch0 = prefix (16 keys, gated; rest masked).
// K/Vt/P LDS all [row][64] bf16 with 16B-slot XOR swizzle: slot ^= (row&7).
__global__ __launch_bounds__(192, 3)
void attn_mfma(const unsigned short* __restrict__ qkv, const float* __restrict__ prompt,
               const float* __restrict__ act_scale, unsigned short* __restrict__ attn_out) {
  const int lg = xcd_swz(blockIdx.x, gridDim.x);
  const int qt = lg % 4, bh = lg / 4;
  const int h = bh % kH, b = bh / kH;
  const int tid = threadIdx.x, wv = tid >> 6, lane = tid & 63;
  const int q15 = lane & 15, kg = lane >> 4;

  __shared__ __align__(16) unsigned short Klds[2][4096];   // [64 k][64 d] swz, 16 KB
  __shared__ __align__(16) unsigned short Vt[2][4096];     // [64 d][64 k] swz, 16 KB
  __shared__ __align__(16) unsigned short Plds[3][3072];   // per-wave [48 q][64 k] swz, 18 KB

  const float a0 = act_scale[0], a1 = act_scale[1];
  const int sw  = q15 & 7;
  const int sl0 = (kg ^ sw) << 3;
  const int sl1 = ((4 + kg) ^ sw) << 3;

  // Q fragments, three groups, pre-scaled by 0.125
  bf16x8 qf[3][2];
#pragma unroll
  for (int g = 0; g < 3; ++g) {
    const unsigned short* qrow =
        qkv + (size_t)(b * kN + qt * 144 + wv * 48 + g * 16 + q15) * 2304 + h * 64;
#pragma unroll
    for (int dh = 0; dh < 2; ++dh) {
      u16x8 raw = *(const u16x8*)(qrow + dh * 32 + kg * 8);
      u16x8 sc;
#pragma unroll
      for (int j = 0; j < 8; ++j) sc[j] = f2bf(bf2f(raw[j]) * 0.125f);
      qf[g][dh] = __builtin_bit_cast(bf16x8, sc);
    }
  }

  // ---- prologue: stage prefix chunk into buf 0 ----
  if (tid < 128) {           // K rows 0..15
    const int r = tid >> 3, s = tid & 7;
    const float* src = prompt + (((size_t)(b * 2) * kP + r) * kH + h) * 64 + s * 8;
    const f32x4 f0 = *(const f32x4*)src, f1 = *(const f32x4*)(src + 4);
    *(uint4*)(&Klds[0][r * 64 + ((s ^ (r & 7)) << 3)]) =
        make_uint4(pk2bf(f0[0], f0[1]), pk2bf(f0[2], f0[3]),
                   pk2bf(f1[0], f1[1]), pk2bf(f1[2], f1[3]));
  }
  if (tid < 128) {           // Vt keys 0..15 (transposed)
    const int kp = tid & 7, vdq = tid >> 3;   // key-pair 0..7, d-quad 0..15
    const float* s0 = prompt + (((size_t)(b * 2 + 1) * kP + 2 * kp) * kH + h) * 64 + vdq * 4;
    const f32x4 x0 = *(const f32x4*)s0;
    const f32x4 y0 = *(const f32x4*)(s0 + kH * 64);
#pragma unroll
    for (int j = 0; j < 4; ++j) {
      const int d = vdq * 4 + j;
      *(unsigned int*)(&Vt[0][d * 64 + (((kp >> 2) ^ (d & 7)) << 3) + (kp & 3) * 2]) =
          pk2bf(x0[j], y0[j]);
    }
  }
#pragma unroll
  for (int i = 0; i < 2; ++i) {   // zero Vt keys 16..63 (slots 2..7 per d-row)
    const int idx = tid + 192 * i;          // 0..383
    const int d = idx / 6, szl = (idx % 6) + 2;
    *(uint4*)(&Vt[0][d * 64 + ((szl ^ (d & 7)) << 3)]) = make_uint4(0, 0, 0, 0);
  }
  __syncthreads();

  f32x4 o0[4] = {}, o1[4] = {}, o2[4] = {};
  float l0 = 0.0f, l1 = 0.0f, l2 = 0.0f;

  const int vkp  = tid & 31;       // waves 0-1: V key-pair
  const int vdgb = tid >> 5;       //            d-octet base (octets vdgb, vdgb+4); 0..3
  const int kr8  = lane >> 3, ks8 = lane & 7;   // wave 2: K staging

  for (int ch = 0; ch < 10; ++ch) {
    const int cur = ch & 1;

    // ---- (1) begin staging chunk ch+1 into buf cur^1 ----
    u16x8 va0, va1, vb0, vb1;
    const bool doV = (ch < 9) && (wv < 2);
    if (ch < 9) {
      if (doV) {                   // V loads now; LDS writes after softmax (T14)
        const unsigned short* r0 = qkv + (size_t)(b * kN + ch * 64 + 2 * vkp) * 2304 + 1536 + h * 64;
        va0 = *(const u16x8*)(r0 + vdgb * 8);
        va1 = *(const u16x8*)(r0 + (vdgb + 4) * 8);
        vb0 = *(const u16x8*)(r0 + 2304 + vdgb * 8);
        vb1 = *(const u16x8*)(r0 + 2304 + (vdgb + 4) * 8);
      } else if (wv == 2) {        // K via glds, pre-swizzled source
#pragma unroll
        for (int g8 = 0; g8 < 8; ++g8) {
          const int r = g8 * 8 + kr8;
          const unsigned short* src =
              qkv + (size_t)(b * kN + ch * 64 + r) * 2304 + 768 + h * 64 + ((ks8 ^ (r & 7)) << 3);
          GLDS16(src, &Klds[cur ^ 1][g8 * 512]);
        }
      }
    }

    // ---- (2) QK^T for all three groups (K frags shared) ----
    f32x4 c0[4], c1[4], c2[4];
    __builtin_amdgcn_s_setprio(1);
#pragma unroll
    for (int kb = 0; kb < 4; ++kb) {
      if (ch == 0 && kb > 0) {
        c0[kb][0] = c0[kb][1] = c0[kb][2] = c0[kb][3] = -1.0e30f;
        c1[kb][0] = c1[kb][1] = c1[kb][2] = c1[kb][3] = -1.0e30f;
        c2[kb][0] = c2[kb][1] = c2[kb][2] = c2[kb][3] = -1.0e30f;
      } else {
        const unsigned short* krow = &Klds[cur][(kb * 16 + q15) * 64];
        const bf16x8 k0 = *(const bf16x8*)(krow + sl0);
        const bf16x8 k1 = *(const bf16x8*)(krow + sl1);
        f32x4 t0 = {}, t1 = {}, t2 = {};
        t0 = __builtin_amdgcn_mfma_f32_16x16x32_bf16(k0, qf[0][0], t0, 0, 0, 0);
        c0[kb] = __builtin_amdgcn_mfma_f32_16x16x32_bf16(k1, qf[0][1], t0, 0, 0, 0);
        t1 = __builtin_amdgcn_mfma_f32_16x16x32_bf16(k0, qf[1][0], t1, 0, 0, 0);
        c1[kb] = __builtin_amdgcn_mfma_f32_16x16x32_bf16(k1, qf[1][1], t1, 0, 0, 0);
        t2 = __builtin_amdgcn_mfma_f32_16x16x32_bf16(k0, qf[2][0], t2, 0, 0, 0);
        c2[kb] = __builtin_amdgcn_mfma_f32_16x16x32_bf16(k1, qf[2][1], t2, 0, 0, 0);
      }
    }
    __builtin_amdgcn_s_setprio(0);
    if (ch == 0) {                  // NoRGa gating on prefix scores
#pragma unroll
      for (int j = 0; j < 4; ++j) {
        const float s0v = c0[0][j];
        const float e0 = __expf(2.0f * s0v * a0);
        c0[0][j] = s0v + ((e0 - 1.0f) / (e0 + 1.0f)) * a1;
        const float s1v = c1[0][j];
        const float e1 = __expf(2.0f * s1v * a0);
        c1[0][j] = s1v + ((e1 - 1.0f) / (e1 + 1.0f)) * a1;
        const float s2v = c2[0][j];
        const float e2 = __expf(2.0f * s2v * a0);
        c2[0][j] = s2v + ((e2 - 1.0f) / (e2 + 1.0f)) * a1;
      }
    }

    // ---- (3) static-shift softmax + P writes (three independent chains) ----
    softmax_group_static(c0, l0, &Plds[wv][q15 * 64], kg, sw);
    softmax_group_static(c1, l1, &Plds[wv][(q15 + 16) * 64], kg, sw);
    softmax_group_static(c2, l2, &Plds[wv][(q15 + 32) * 64], kg, sw);

    // ---- (4) write staged V (loads have landed under QK/softmax) ----
    if (doV) {
#pragma unroll
      for (int j = 0; j < 8; ++j) {
        const int d0 = vdgb * 8 + j;
        *(unsigned int*)(&Vt[cur ^ 1][d0 * 64 + (((vkp >> 2) ^ (d0 & 7)) << 3) + (vkp & 3) * 2]) =
            (unsigned int)va0[j] | ((unsigned int)vb0[j] << 16);
        const int d1 = (vdgb + 4) * 8 + j;
        *(unsigned int*)(&Vt[cur ^ 1][d1 * 64 + (((vkp >> 2) ^ (d1 & 7)) << 3) + (vkp & 3) * 2]) =
            (unsigned int)va1[j] | ((unsigned int)vb1[j] << 16);
      }
    }

    // ---- (5) PV for all three groups (Vt frags shared) ----
    const unsigned short* p0 = &Plds[wv][q15 * 64];
    const unsigned short* p1 = &Plds[wv][(q15 + 16) * 64];
    const unsigned short* p2 = &Plds[wv][(q15 + 32) * 64];
    const bf16x8 pa00 = *(const bf16x8*)(p0 + sl0);
    const bf16x8 pa01 = *(const bf16x8*)(p0 + sl1);
    const bf16x8 pa10 = *(const bf16x8*)(p1 + sl0);
    const bf16x8 pa11 = *(const bf16x8*)(p1 + sl1);
    const bf16x8 pa20 = *(const bf16x8*)(p2 + sl0);
    const bf16x8 pa21 = *(const bf16x8*)(p2 + sl1);
    __builtin_amdgcn_s_setprio(1);
#pragma unroll
    for (int nb = 0; nb < 4; ++nb) {
      const unsigned short* vr = &Vt[cur][(nb * 16 + q15) * 64];
      const bf16x8 bv0 = *(const bf16x8*)(vr + sl0);
      const bf16x8 bv1 = *(const bf16x8*)(vr + sl1);
      o0[nb] = __builtin_amdgcn_mfma_f32_16x16x32_bf16(pa00, bv0, o0[nb], 0, 0, 0);
      o0[nb] = __builtin_amdgcn_mfma_f32_16x16x32_bf16(pa01, bv1, o0[nb], 0, 0, 0);
      o1[nb] = __builtin_amdgcn_mfma_f32_16x16x32_bf16(pa10, bv0, o1[nb], 0, 0, 0);
      o1[nb] = __builtin_amdgcn_mfma_f32_16x16x32_bf16(pa11, bv1, o1[nb], 0, 0, 0);
      o2[nb] = __builtin_amdgcn_mfma_f32_16x16x32_bf16(pa20, bv0, o2[nb], 0, 0, 0);
      o2[nb] = __builtin_amdgcn_mfma_f32_16x16x32_bf16(pa21, bv1, o2[nb], 0, 0, 0);
    }
    __builtin_amdgcn_s_setprio(0);

    __syncthreads();   // staging of buf^1 complete (drains glds vmcnt); reads of buf done
  }

  // ---- epilogue: reduce l across kg groups, normalize, store bf16 ----
  l0 += __shfl_xor(l0, 16, 64);
  l0 += __shfl_xor(l0, 32, 64);
  l1 += __shfl_xor(l1, 16, 64);
  l1 += __shfl_xor(l1, 32, 64);
  l2 += __shfl_xor(l2, 16, 64);
  l2 += __shfl_xor(l2, 32, 64);
  const float i0 = 1.0f / l0, i1 = 1.0f / l1, i2 = 1.0f / l2;
  float iq0[4], iq1[4], iq2[4];
#pragma unroll
  for (int jr = 0; jr < 4; ++jr) {
    iq0[jr] = __shfl(i0, kg * 4 + jr, 64);
    iq1[jr] = __shfl(i1, kg * 4 + jr, 64);
    iq2[jr] = __shfl(i2, kg * 4 + jr, 64);
  }
  unsigned short* ob = attn_out + (size_t)(b * kN + qt * 144 + wv * 48) * 768 + h * 64;
#pragma unroll
  for (int nb = 0; nb < 4; ++nb)
#pragma unroll
    for (int jr = 0; jr < 4; ++jr) {
      ob[(size_t)(kg * 4 + jr) * 768 + nb * 16 + q15] = f2bf(o0[nb][jr] * iq0[jr]);
      ob[(size_t)(16 + kg * 4 + jr) * 768 + nb * 16 + q15] = f2bf(o1[nb][jr] * iq1[jr]);
      ob[(size_t)(32 + kg * 4 + jr) * 768 + nb * 16 + q15] = f2bf(o2[nb][jr] * iq2[jr]);
    }
}

} // namespace

extern "C" void kernel_launch(void* const* d_in, const int* in_sizes, int n_in,
                              void* d_out, int out_size, void* d_ws, size_t ws_size,
                              hipStream_t stream) {
  const float* x         = (const float*)d_in[0];
  const float* prompt    = (const float*)d_in[1];
  const float* act_scale = (const float*)d_in[2];
  const float* qkv_w     = (const float*)d_in[3];
  const float* proj_w    = (const float*)d_in[4];
  const float* proj_b    = (const float*)d_in[5];
  float* out = (float*)d_out;

  // Workspace: qkv_bf16 [9216,2304] 42.5MB | xa_bf16 [9216,768] 14.2MB (x, then attn out)
  //            qkvw_bf16 3.5MB | projw_bf16 1.2MB
  char* ws = (char*)d_ws;
  unsigned short* qkvb   = (unsigned short*)ws;
  unsigned short* xa     = (unsigned short*)(ws + 42467328);
  unsigned short* qkvwb  = (unsigned short*)(ws + 42467328 + 14155776);
  unsigned short* projwb = (unsigned short*)(ws + 42467328 + 14155776 + 3538944);

  cvt3<<<9216, 256, 0, stream>>>(x, qkv_w, proj_w, xa, qkvwb, projwb);

  // 1) qkv = x @ qkv_w^T  -> bf16   (grid 1296 = 8*162)
  gemm_bf16<1, kC><<<(3 * kC / 128) * (kM / 128), 256, 0, stream>>>(xa, qkvwb, nullptr, qkvb, 3 * kC);
  // 2) fused gated-prefix MFMA attention -> bf16 (grid 768 = 8*96, 144 q/block, 3 waves x 3 groups)
  attn_mfma<<<(kN / 144) * kH * kB, 192, 0, stream>>>(qkvb, prompt, act_scale, xa);
  // 3) out = attn @ proj_w^T + proj_b  -> f32  (grid 432 = 8*54)
  gemm_bf16<0, kC><<<(kC / 128) * (kM / 128), 256, 0, stream>>>(xa, projwb, proj_b, out, kC);
}

// Round 23
// 116.706 us; speedup vs baseline: 1.3868x; 1.3868x over previous
//
#include <hip/hip_runtime.h>
#include <hip/hip_bf16.h>
#include <math.h>

namespace {

constexpr int kB = 16, kN = 576, kC = 768, kH = 12, kP = 16;
constexpr int kM = kB * kN;          // 9216 rows

typedef __attribute__((ext_vector_type(8))) __bf16 bf16x8;
typedef __attribute__((ext_vector_type(4))) float  f32x4;
typedef __attribute__((ext_vector_type(8))) unsigned short u16x8;

__device__ inline unsigned short f2bf(float f) {
  __bf16 h = (__bf16)f;
  return __builtin_bit_cast(unsigned short, h);
}
__device__ inline float bf2f(unsigned short u) {
  unsigned int x = ((unsigned int)u) << 16;
  return __builtin_bit_cast(float, x);
}
__device__ inline unsigned int pk2bf(float lo, float hi) {
  return (unsigned int)f2bf(lo) | ((unsigned int)f2bf(hi) << 16);
}
// XCD-contiguous bijective remap (nwg % 8 == 0)
__device__ inline int xcd_swz(int hw, int nwg) {
  const int per = nwg >> 3;
  return (hw & 7) * per + (hw >> 3);
}

#define GLDS16(src, dst) __builtin_amdgcn_global_load_lds( \
    (const __attribute__((address_space(1))) unsigned int*)(src), \
    (__attribute__((address_space(3))) unsigned int*)(dst), 16, 0, 0)

// fused fp32->bf16 for x (6912 blocks), qkv_w (1728), proj_w (576)
__global__ __launch_bounds__(256)
void cvt3(const float* __restrict__ x, const float* __restrict__ wq,
          const float* __restrict__ wp, unsigned short* __restrict__ xo,
          unsigned short* __restrict__ wqo, unsigned short* __restrict__ wpo) {
  const int bid = blockIdx.x;
  const float* in; unsigned short* out; int base;
  if (bid < 6912)       { in = x;  out = xo;  base = bid; }
  else if (bid < 8640)  { in = wq; out = wqo; base = bid - 6912; }
  else                  { in = wp; out = wpo; base = bid - 8640; }
  const int i = base * 256 + threadIdx.x;
  const float4 v = ((const float4*)in)[i];
  ((ushort4*)out)[i] = make_ushort4(f2bf(v.x), f2bf(v.y), f2bf(v.z), f2bf(v.w));
}

// Y[M,Nd] = A[M,Kd](bf16) @ W[Nd,Kd](bf16)^T. OB=1: bf16 out; OB=0: f32 out + bias.
// 128x128 tile, BK=64 (12 K-steps), SINGLE LDS buffer (32 KB), register-staged
// prefetch. Rows = 128B = 8 slots, XOR swizzle slot^=(row&7) write-side.
// (R15/R17-verified, frozen. Session GEMM floor ~51 us: counted-vmcnt, buffer
// depth, wave-tile, BK, B-direct all measured null/negative around it.)
template<int OB>
__global__ __launch_bounds__(256)
void gemm_bf16(const unsigned short* __restrict__ A, const unsigned short* __restrict__ W,
               const float* __restrict__ bias, void* __restrict__ Yv, int Kd, int Nd) {
  __shared__ __align__(16) unsigned short As[8192];   // 128 rows x 64 k, swizzled
  __shared__ __align__(16) unsigned short Bs[8192];
  const int tid  = threadIdx.x;
  const int wv   = tid >> 6, lane = tid & 63;
  const int gx   = Nd >> 7;
  const int lg   = xcd_swz(blockIdx.x, gridDim.x);
  const long bm  = (long)(lg / gx) * 128;
  const long bn  = (long)(lg % gx) * 128;
  const int wr   = (wv >> 1) * 64;
  const int wc   = (wv & 1) * 64;
  const int row15 = lane & 15, kg = lane >> 4;

  u16x8 ra[4], rb[4];
  auto loadregs = [&](int kt) {
#pragma unroll
    for (int site = 0; site < 4; ++site) {
      const int u = site * 256 + tid;
      const int row = u >> 3, slot = u & 7;
      ra[site] = *(const u16x8*)(A + (bm + row) * (long)Kd + kt + slot * 8);
      rb[site] = *(const u16x8*)(W + (bn + row) * (long)Kd + kt + slot * 8);
    }
  };
  auto writeLDS = [&]() {
#pragma unroll
    for (int site = 0; site < 4; ++site) {
      const int u = site * 256 + tid;
      const int row = u >> 3, slot = u & 7;
      const int off = row * 64 + ((slot ^ (row & 7)) << 3);
      *(u16x8*)(As + off) = ra[site];
      *(u16x8*)(Bs + off) = rb[site];
    }
  };

  float bvpre[4] = {0.0f, 0.0f, 0.0f, 0.0f};
  if constexpr (!OB) {
#pragma unroll
    for (int ni = 0; ni < 4; ++ni) bvpre[ni] = bias[bn + wc + ni * 16 + row15];
  }

  f32x4 acc[4][4] = {};
  loadregs(0);
  writeLDS();

  const int sw8 = row15 & 7;
  const int nt = Kd >> 6;        // 12 steps
  for (int t = 0; t < nt; ++t) {
    __syncthreads();             // B1: tile t writes visible
    if (t + 1 < nt) loadregs((t + 1) << 6);

    bf16x8 af[4][2], bf_[4][2];
#pragma unroll
    for (int mi = 0; mi < 4; ++mi)
#pragma unroll
      for (int ks = 0; ks < 2; ++ks)
        af[mi][ks] = *(const bf16x8*)(&As[(wr + mi * 16 + row15) * 64 +
                                          (((ks * 4 + kg) ^ sw8) << 3)]);
#pragma unroll
    for (int ni = 0; ni < 4; ++ni)
#pragma unroll
      for (int ks = 0; ks < 2; ++ks)
        bf_[ni][ks] = *(const bf16x8*)(&Bs[(wc + ni * 16 + row15) * 64 +
                                           (((ks * 4 + kg) ^ sw8) << 3)]);
    __builtin_amdgcn_s_setprio(1);
#pragma unroll
    for (int ks = 0; ks < 2; ++ks)
#pragma unroll
      for (int mi = 0; mi < 4; ++mi)
#pragma unroll
        for (int ni = 0; ni < 4; ++ni)
          acc[mi][ni] = __builtin_amdgcn_mfma_f32_16x16x32_bf16(af[mi][ks], bf_[ni][ks],
                                                                acc[mi][ni], 0, 0, 0);
    __builtin_amdgcn_s_setprio(0);
    __syncthreads();             // B2: all reads of tile t done
    if (t + 1 < nt) writeLDS();
  }

  const int r4 = kg * 4;
#pragma unroll
  for (int ni = 0; ni < 4; ++ni) {
    const long col = bn + wc + ni * 16 + row15;
    if constexpr (OB) {
      unsigned short* Y = (unsigned short*)Yv;
#pragma unroll
      for (int mi = 0; mi < 4; ++mi)
#pragma unroll
        for (int j = 0; j < 4; ++j)
          Y[(bm + wr + mi * 16 + r4 + j) * (long)Nd + col] = f2bf(acc[mi][ni][j]);
    } else {
      float* Y = (float*)Yv;
#pragma unroll
      for (int mi = 0; mi < 4; ++mi)
#pragma unroll
        for (int j = 0; j < 4; ++j)
          Y[(bm + wr + mi * 16 + r4 + j) * (long)Nd + col] = acc[mi][ni][j] + bvpre[ni];
    }
  }
}

// Static-shift softmax: p = exp(s - 10). No max tracking, no rescale, no cross-lane
// per chunk; per-lane partial sum only. Exact up to common scale (normalized at end).
__device__ inline void softmax_group_static(f32x4 (&c)[4], float& lsum,
                                            unsigned short* pl,
                                            const int kg, const int sw) {
  float psum = 0.0f;
#pragma unroll
  for (int kb = 0; kb < 4; ++kb) {
    const float p0 = __expf(c[kb][0] - 10.0f);
    const float p1 = __expf(c[kb][1] - 10.0f);
    const float p2 = __expf(c[kb][2] - 10.0f);
    const float p3 = __expf(c[kb][3] - 10.0f);
    psum += (p0 + p1) + (p2 + p3);
    const int off = (((kb * 2 + (kg >> 1)) ^ sw) << 3) + (kg & 1) * 4;
    *(uint2*)(pl + off) = make_uint2(pk2bf(p0, p1), pk2bf(p2, p3));
  }
  lsum += psum;
}

// MFMA flash attention with gated 16-key prefix (R18-verified, frozen).
// Block = 192 thr (3 waves); each wave owns THREE 16-query groups (48 q/wave,
// 144 q/block). KV chunk = 64 keys; ch0 = prefix (16 keys, gated; rest masked).
// K/Vt/P LDS all [row][64] bf16 with 16B-slot XOR swizzle: slot ^= (row&7).
__global__ __launch_bounds__(192, 3)
void attn_mfma(const unsigned short* __restrict__ qkv, const float* __restrict__ prompt,
               const float* __restrict__ act_scale, unsigned short* __restrict__ attn_out) {
  const int lg = xcd_swz(blockIdx.x, gridDim.x);
  const int qt = lg % 4, bh = lg / 4;
  const int h = bh % kH, b = bh / kH;
  const int tid = threadIdx.x, wv = tid >> 6, lane = tid & 63;
  const int q15 = lane & 15, kg = lane >> 4;

  __shared__ __align__(16) unsigned short Klds[2][4096];   // [64 k][64 d] swz, 16 KB
  __shared__ __align__(16) unsigned short Vt[2][4096];     // [64 d][64 k] swz, 16 KB
  __shared__ __align__(16) unsigned short Plds[3][3072];   // per-wave [48 q][64 k] swz, 18 KB

  const float a0 = act_scale[0], a1 = act_scale[1];
  const int sw  = q15 & 7;
  const int sl0 = (kg ^ sw) << 3;
  const int sl1 = ((4 + kg) ^ sw) << 3;

  // Q fragments, three groups, pre-scaled by 0.125
  bf16x8 qf[3][2];
#pragma unroll
  for (int g = 0; g < 3; ++g) {
    const unsigned short* qrow =
        qkv + (size_t)(b * kN + qt * 144 + wv * 48 + g * 16 + q15) * 2304 + h * 64;
#pragma unroll
    for (int dh = 0; dh < 2; ++dh) {
      u16x8 raw = *(const u16x8*)(qrow + dh * 32 + kg * 8);
      u16x8 sc;
#pragma unroll
      for (int j = 0; j < 8; ++j) sc[j] = f2bf(bf2f(raw[j]) * 0.125f);
      qf[g][dh] = __builtin_bit_cast(bf16x8, sc);
    }
  }

  // ---- prologue: stage prefix chunk into buf 0 ----
  if (tid < 128) {           // K rows 0..15
    const int r = tid >> 3, s = tid & 7;
    const float* src = prompt + (((size_t)(b * 2) * kP + r) * kH + h) * 64 + s * 8;
    const f32x4 f0 = *(const f32x4*)src, f1 = *(const f32x4*)(src + 4);
    *(uint4*)(&Klds[0][r * 64 + ((s ^ (r & 7)) << 3)]) =
        make_uint4(pk2bf(f0[0], f0[1]), pk2bf(f0[2], f0[3]),
                   pk2bf(f1[0], f1[1]), pk2bf(f1[2], f1[3]));
  }
  if (tid < 128) {           // Vt keys 0..15 (transposed)
    const int kp = tid & 7, vdq = tid >> 3;   // key-pair 0..7, d-quad 0..15
    const float* s0 = prompt + (((size_t)(b * 2 + 1) * kP + 2 * kp) * kH + h) * 64 + vdq * 4;
    const f32x4 x0 = *(const f32x4*)s0;
    const f32x4 y0 = *(const f32x4*)(s0 + kH * 64);
#pragma unroll
    for (int j = 0; j < 4; ++j) {
      const int d = vdq * 4 + j;
      *(unsigned int*)(&Vt[0][d * 64 + (((kp >> 2) ^ (d & 7)) << 3) + (kp & 3) * 2]) =
          pk2bf(x0[j], y0[j]);
    }
  }
#pragma unroll
  for (int i = 0; i < 2; ++i) {   // zero Vt keys 16..63 (slots 2..7 per d-row)
    const int idx = tid + 192 * i;          // 0..383
    const int d = idx / 6, szl = (idx % 6) + 2;
    *(uint4*)(&Vt[0][d * 64 + ((szl ^ (d & 7)) << 3)]) = make_uint4(0, 0, 0, 0);
  }
  __syncthreads();

  f32x4 o0[4] = {}, o1[4] = {}, o2[4] = {};
  float l0 = 0.0f, l1 = 0.0f, l2 = 0.0f;

  const int vkp  = tid & 31;       // waves 0-1: V key-pair
  const int vdgb = tid >> 5;       //            d-octet base (octets vdgb, vdgb+4); 0..3
  const int kr8  = lane >> 3, ks8 = lane & 7;   // wave 2: K staging

  for (int ch = 0; ch < 10; ++ch) {
    const int cur = ch & 1;

    // ---- (1) begin staging chunk ch+1 into buf cur^1 ----
    u16x8 va0, va1, vb0, vb1;
    const bool doV = (ch < 9) && (wv < 2);
    if (ch < 9) {
      if (doV) {                   // V loads now; LDS writes after softmax (T14)
        const unsigned short* r0 = qkv + (size_t)(b * kN + ch * 64 + 2 * vkp) * 2304 + 1536 + h * 64;
        va0 = *(const u16x8*)(r0 + vdgb * 8);
        va1 = *(const u16x8*)(r0 + (vdgb + 4) * 8);
        vb0 = *(const u16x8*)(r0 + 2304 + vdgb * 8);
        vb1 = *(const u16x8*)(r0 + 2304 + (vdgb + 4) * 8);
      } else if (wv == 2) {        // K via glds, pre-swizzled source
#pragma unroll
        for (int g8 = 0; g8 < 8; ++g8) {
          const int r = g8 * 8 + kr8;
          const unsigned short* src =
              qkv + (size_t)(b * kN + ch * 64 + r) * 2304 + 768 + h * 64 + ((ks8 ^ (r & 7)) << 3);
          GLDS16(src, &Klds[cur ^ 1][g8 * 512]);
        }
      }
    }

    // ---- (2) QK^T for all three groups (K frags shared) ----
    f32x4 c0[4], c1[4], c2[4];
    __builtin_amdgcn_s_setprio(1);
#pragma unroll
    for (int kb = 0; kb < 4; ++kb) {
      if (ch == 0 && kb > 0) {
        c0[kb][0] = c0[kb][1] = c0[kb][2] = c0[kb][3] = -1.0e30f;
        c1[kb][0] = c1[kb][1] = c1[kb][2] = c1[kb][3] = -1.0e30f;
        c2[kb][0] = c2[kb][1] = c2[kb][2] = c2[kb][3] = -1.0e30f;
      } else {
        const unsigned short* krow = &Klds[cur][(kb * 16 + q15) * 64];
        const bf16x8 k0 = *(const bf16x8*)(krow + sl0);
        const bf16x8 k1 = *(const bf16x8*)(krow + sl1);
        f32x4 t0 = {}, t1 = {}, t2 = {};
        t0 = __builtin_amdgcn_mfma_f32_16x16x32_bf16(k0, qf[0][0], t0, 0, 0, 0);
        c0[kb] = __builtin_amdgcn_mfma_f32_16x16x32_bf16(k1, qf[0][1], t0, 0, 0, 0);
        t1 = __builtin_amdgcn_mfma_f32_16x16x32_bf16(k0, qf[1][0], t1, 0, 0, 0);
        c1[kb] = __builtin_amdgcn_mfma_f32_16x16x32_bf16(k1, qf[1][1], t1, 0, 0, 0);
        t2 = __builtin_amdgcn_mfma_f32_16x16x32_bf16(k0, qf[2][0], t2, 0, 0, 0);
        c2[kb] = __builtin_amdgcn_mfma_f32_16x16x32_bf16(k1, qf[2][1], t2, 0, 0, 0);
      }
    }
    __builtin_amdgcn_s_setprio(0);
    if (ch == 0) {                  // NoRGa gating on prefix scores
#pragma unroll
      for (int j = 0; j < 4; ++j) {
        const float s0v = c0[0][j];
        const float e0 = __expf(2.0f * s0v * a0);
        c0[0][j] = s0v + ((e0 - 1.0f) / (e0 + 1.0f)) * a1;
        const float s1v = c1[0][j];
        const float e1 = __expf(2.0f * s1v * a0);
        c1[0][j] = s1v + ((e1 - 1.0f) / (e1 + 1.0f)) * a1;
        const float s2v = c2[0][j];
        const float e2 = __expf(2.0f * s2v * a0);
        c2[0][j] = s2v + ((e2 - 1.0f) / (e2 + 1.0f)) * a1;
      }
    }

    // ---- (3) static-shift softmax + P writes (three independent chains) ----
    softmax_group_static(c0, l0, &Plds[wv][q15 * 64], kg, sw);
    softmax_group_static(c1, l1, &Plds[wv][(q15 + 16) * 64], kg, sw);
    softmax_group_static(c2, l2, &Plds[wv][(q15 + 32) * 64], kg, sw);

    // ---- (4) write staged V (loads have landed under QK/softmax) ----
    if (doV) {
#pragma unroll
      for (int j = 0; j < 8; ++j) {
        const int d0 = vdgb * 8 + j;
        *(unsigned int*)(&Vt[cur ^ 1][d0 * 64 + (((vkp >> 2) ^ (d0 & 7)) << 3) + (vkp & 3) * 2]) =
            (unsigned int)va0[j] | ((unsigned int)vb0[j] << 16);
        const int d1 = (vdgb + 4) * 8 + j;
        *(unsigned int*)(&Vt[cur ^ 1][d1 * 64 + (((vkp >> 2) ^ (d1 & 7)) << 3) + (vkp & 3) * 2]) =
            (unsigned int)va1[j] | ((unsigned int)vb1[j] << 16);
      }
    }

    // ---- (5) PV for all three groups (Vt frags shared) ----
    const unsigned short* p0 = &Plds[wv][q15 * 64];
    const unsigned short* p1 = &Plds[wv][(q15 + 16) * 64];
    const unsigned short* p2 = &Plds[wv][(q15 + 32) * 64];
    const bf16x8 pa00 = *(const bf16x8*)(p0 + sl0);
    const bf16x8 pa01 = *(const bf16x8*)(p0 + sl1);
    const bf16x8 pa10 = *(const bf16x8*)(p1 + sl0);
    const bf16x8 pa11 = *(const bf16x8*)(p1 + sl1);
    const bf16x8 pa20 = *(const bf16x8*)(p2 + sl0);
    const bf16x8 pa21 = *(const bf16x8*)(p2 + sl1);
    __builtin_amdgcn_s_setprio(1);
#pragma unroll
    for (int nb = 0; nb < 4; ++nb) {
      const unsigned short* vr = &Vt[cur][(nb * 16 + q15) * 64];
      const bf16x8 bv0 = *(const bf16x8*)(vr + sl0);
      const bf16x8 bv1 = *(const bf16x8*)(vr + sl1);
      o0[nb] = __builtin_amdgcn_mfma_f32_16x16x32_bf16(pa00, bv0, o0[nb], 0, 0, 0);
      o0[nb] = __builtin_amdgcn_mfma_f32_16x16x32_bf16(pa01, bv1, o0[nb], 0, 0, 0);
      o1[nb] = __builtin_amdgcn_mfma_f32_16x16x32_bf16(pa10, bv0, o1[nb], 0, 0, 0);
      o1[nb] = __builtin_amdgcn_mfma_f32_16x16x32_bf16(pa11, bv1, o1[nb], 0, 0, 0);
      o2[nb] = __builtin_amdgcn_mfma_f32_16x16x32_bf16(pa20, bv0, o2[nb], 0, 0, 0);
      o2[nb] = __builtin_amdgcn_mfma_f32_16x16x32_bf16(pa21, bv1, o2[nb], 0, 0, 0);
    }
    __builtin_amdgcn_s_setprio(0);

    __syncthreads();   // staging of buf^1 complete (drains glds vmcnt); reads of buf done
  }

  // ---- epilogue: reduce l across kg groups, normalize, store bf16 ----
  l0 += __shfl_xor(l0, 16, 64);
  l0 += __shfl_xor(l0, 32, 64);
  l1 += __shfl_xor(l1, 16, 64);
  l1 += __shfl_xor(l1, 32, 64);
  l2 += __shfl_xor(l2, 16, 64);
  l2 += __shfl_xor(l2, 32, 64);
  const float i0 = 1.0f / l0, i1 = 1.0f / l1, i2 = 1.0f / l2;
  float iq0[4], iq1[4], iq2[4];
#pragma unroll
  for (int jr = 0; jr < 4; ++jr) {
    iq0[jr] = __shfl(i0, kg * 4 + jr, 64);
    iq1[jr] = __shfl(i1, kg * 4 + jr, 64);
    iq2[jr] = __shfl(i2, kg * 4 + jr, 64);
  }
  unsigned short* ob = attn_out + (size_t)(b * kN + qt * 144 + wv * 48) * 768 + h * 64;
#pragma unroll
  for (int nb = 0; nb < 4; ++nb)
#pragma unroll
    for (int jr = 0; jr < 4; ++jr) {
      ob[(size_t)(kg * 4 + jr) * 768 + nb * 16 + q15] = f2bf(o0[nb][jr] * iq0[jr]);
      ob[(size_t)(16 + kg * 4 + jr) * 768 + nb * 16 + q15] = f2bf(o1[nb][jr] * iq1[jr]);
      ob[(size_t)(32 + kg * 4 + jr) * 768 + nb * 16 + q15] = f2bf(o2[nb][jr] * iq2[jr]);
    }
}

} // namespace

extern "C" void kernel_launch(void* const* d_in, const int* in_sizes, int n_in,
                              void* d_out, int out_size, void* d_ws, size_t ws_size,
                              hipStream_t stream) {
  const float* x         = (const float*)d_in[0];
  const float* prompt    = (const float*)d_in[1];
  const float* act_scale = (const float*)d_in[2];
  const float* qkv_w     = (const float*)d_in[3];
  const float* proj_w    = (const float*)d_in[4];
  const float* proj_b    = (const float*)d_in[5];
  float* out = (float*)d_out;

  // Workspace: qkv_bf16 [9216,2304] 42.5MB | xa_bf16 [9216,768] 14.2MB (x, then attn out)
  //            qkvw_bf16 3.5MB | projw_bf16 1.2MB
  char* ws = (char*)d_ws;
  unsigned short* qkvb   = (unsigned short*)ws;
  unsigned short* xa     = (unsigned short*)(ws + 42467328);
  unsigned short* qkvwb  = (unsigned short*)(ws + 42467328 + 14155776);
  unsigned short* projwb = (unsigned short*)(ws + 42467328 + 14155776 + 3538944);

  cvt3<<<9216, 256, 0, stream>>>(x, qkv_w, proj_w, xa, qkvwb, projwb);

  // 1) qkv = x @ qkv_w^T  -> bf16   (grid 1296 = 8*162)
  gemm_bf16<1><<<(3 * kC / 128) * (kM / 128), 256, 0, stream>>>(xa, qkvwb, nullptr, qkvb, kC, 3 * kC);
  // 2) fused gated-prefix MFMA attention -> bf16 (grid 768 = 8*96, 144 q/block, 3 waves x 3 groups)
  attn_mfma<<<(kN / 144) * kH * kB, 192, 0, stream>>>(qkvb, prompt, act_scale, xa);
  // 3) out = attn @ proj_w^T + proj_b  -> f32  (grid 432 = 8*54)
  gemm_bf16<0><<<(kC / 128) * (kM / 128), 256, 0, stream>>>(xa, projwb, proj_b, out, kC, kC);
}